// Round 3
// baseline (1012.060 us; speedup 1.0000x reference)
//
#include <hip/hip_runtime.h>
#include <cstdio>

// Qwen2 MoE sparse block, MI355X gfx950.
// Round 3: back to proven 128x128/BK=32 GEMM core (R1) + R2's conflict-free
// source swizzle. New: contiguous token pre-gather (no scattered A in GEMM),
// all gate-up GEMMs fused into one dispatch (shared + 8 experts), all down
// GEMMs fused into one dispatch (shared split-K=4 atomics + experts),
// XCD-aware block swizzle. Goal: 4-8 blocks/CU resident (TLP latency hiding).

#define H_DIM 2048
#define IMOE  1408
#define ISH   5632
#define NEXP  8
#define T_TOK 2048
#define TK_TOT (T_TOK * 2)

typedef __attribute__((ext_vector_type(8))) short short8;
typedef __attribute__((ext_vector_type(8))) __bf16 bf16x8;
typedef __attribute__((ext_vector_type(4))) float f32x4;

__device__ __forceinline__ float bf2f(unsigned short u) {
  union { unsigned int i; float f; } v; v.i = ((unsigned int)u) << 16; return v.f;
}
__device__ __forceinline__ unsigned short f2bf(float f) {
  union { float f; unsigned int i; } v; v.f = f;
  unsigned int x = v.i;
  return (unsigned short)((x + 0x7fffu + ((x >> 16) & 1u)) >> 16);
}

__device__ __forceinline__ f32x4 MFMA16(short8 a, short8 b, f32x4 c) {
  return __builtin_amdgcn_mfma_f32_16x16x32_bf16(
      __builtin_bit_cast(bf16x8, a), __builtin_bit_cast(bf16x8, b), c, 0, 0, 0);
}

__device__ __forceinline__ void gload_lds16(const unsigned short* g, unsigned short* l) {
  __builtin_amdgcn_global_load_lds(
      (const __attribute__((address_space(1))) unsigned int*)g,
      (__attribute__((address_space(3))) unsigned int*)l, 16, 0, 0);
}

__device__ __forceinline__ float silu_f(float x) { return x / (1.0f + __expf(-x)); }

// ---------------- conversion kernels ----------------

__global__ __launch_bounds__(256)
void transpose_cvt_kernel(const float* __restrict__ src, unsigned short* __restrict__ dst,
                          int R, int C, long sStride, long dStride) {
  src += (long)blockIdx.z * sStride;
  dst += (long)blockIdx.z * dStride;
  __shared__ float tile[32][33];
  int tx = threadIdx.x, ty = threadIdx.y;           // 32 x 8
  int x = blockIdx.x * 32 + tx;
  int yb = blockIdx.y * 32;
#pragma unroll
  for (int j = 0; j < 4; j++) {
    int y = yb + ty + j * 8;
    tile[ty + j * 8][tx] = src[(long)y * C + x];
  }
  __syncthreads();
  int c = blockIdx.x * 32 + ty;
  int r = yb + tx;
#pragma unroll
  for (int j = 0; j < 4; j++) {
    dst[(long)(c + j * 8) * R + r] = f2bf(tile[tx][ty + j * 8]);
  }
}

__global__ __launch_bounds__(256)
void cvt_x_kernel(const float* __restrict__ x, unsigned short* __restrict__ xb, int total4) {
  int i = blockIdx.x * 256 + threadIdx.x;
  if (i >= total4) return;
  float4 v = ((const float4*)x)[i];
  ushort4 o;
  o.x = f2bf(v.x); o.y = f2bf(v.y); o.z = f2bf(v.z); o.w = f2bf(v.w);
  ((ushort4*)xb)[i] = o;
}

// ---------------- routing ----------------

__global__ __launch_bounds__(256)
void router_kernel(const float* __restrict__ x, const float* __restrict__ Wr,
                   const float* __restrict__ Wsg, float* __restrict__ rw,
                   int* __restrict__ sel, float* __restrict__ sgate_sig,
                   int* __restrict__ counts) {
  int t = blockIdx.x;
  const float* xr = x + (long)t * H_DIM;
  float p[9];
#pragma unroll
  for (int e = 0; e < 9; e++) p[e] = 0.0f;
  for (int h = threadIdx.x; h < H_DIM; h += 256) {
    float xv = xr[h];
#pragma unroll
    for (int e = 0; e < 8; e++) p[e] += xv * Wr[e * H_DIM + h];
    p[8] += xv * Wsg[h];
  }
#pragma unroll
  for (int e = 0; e < 9; e++)
    for (int off = 32; off > 0; off >>= 1)
      p[e] += __shfl_down(p[e], off, 64);
  __shared__ float red[4][9];
  int wave = threadIdx.x >> 6, lane = threadIdx.x & 63;
  if (lane == 0) {
#pragma unroll
    for (int e = 0; e < 9; e++) red[wave][e] = p[e];
  }
  __syncthreads();
  if (threadIdx.x == 0) {
    float lg[9];
#pragma unroll
    for (int e = 0; e < 9; e++) lg[e] = red[0][e] + red[1][e] + red[2][e] + red[3][e];
    float m = lg[0];
#pragma unroll
    for (int e = 1; e < 8; e++) m = fmaxf(m, lg[e]);
    float pr[8], s = 0.0f;
#pragma unroll
    for (int e = 0; e < 8; e++) { pr[e] = expf(lg[e] - m); s += pr[e]; }
    float inv = 1.0f / s;
#pragma unroll
    for (int e = 0; e < 8; e++) pr[e] *= inv;
    int i0 = 0;
#pragma unroll
    for (int e = 1; e < 8; e++) if (pr[e] > pr[i0]) i0 = e;
    int i1 = (i0 == 0) ? 1 : 0;
#pragma unroll
    for (int e = 0; e < 8; e++) if (e != i0 && pr[e] > pr[i1]) i1 = e;
    rw[t * 2] = pr[i0]; rw[t * 2 + 1] = pr[i1];
    sel[t * 2] = i0;    sel[t * 2 + 1] = i1;
    sgate_sig[t] = 1.0f / (1.0f + expf(-lg[8]));
    atomicAdd(&counts[i0], 1);
    atomicAdd(&counts[i1], 1);
  }
}

__global__ void scan_kernel(const int* __restrict__ counts, int* __restrict__ offsets) {
  if (threadIdx.x == 0 && blockIdx.x == 0) {
    int s = 0;
    for (int e = 0; e < NEXP; e++) { offsets[e] = s; s += counts[e]; }
    offsets[NEXP] = s;
  }
}

__global__ __launch_bounds__(256)
void scatter_kernel(const int* __restrict__ sel, const int* __restrict__ offsets,
                    int* __restrict__ cursor, int* __restrict__ tok_of_slot,
                    int* __restrict__ slot_of_tok) {
  int t = blockIdx.x * 256 + threadIdx.x;
  if (t >= T_TOK) return;
#pragma unroll
  for (int k = 0; k < 2; k++) {
    int e = sel[t * 2 + k];
    int pos = atomicAdd(&cursor[e], 1);
    int slot = offsets[e] + pos;
    tok_of_slot[slot] = t;
    slot_of_tok[t * 2 + k] = slot;
  }
}

// contiguous per-slot activation matrix: xg[slot] = xbf[tok_of_slot[slot]]
__global__ __launch_bounds__(256)
void gather_kernel(const unsigned short* __restrict__ xbf, const int* __restrict__ tok,
                   unsigned short* __restrict__ xg) {
  int i = blockIdx.x * 256 + threadIdx.x;   // slot*256 + col16B
  int slot = i >> 8, c8 = i & 255;
  long src = (long)tok[slot] * H_DIM + c8 * 8;
  ulonglong2 v = *(const ulonglong2*)(xbf + src);
  ((ulonglong2*)xg)[i] = v;
}

// ---------------- fused GEMM (128x128 tile, BK=32) ----------------
// PHASE 0 (gate-up): job "shared": gu_sh[2048,11264] = xbf * WsguT^T  (1408 blk)
//                    job "expert e": gu_e[slots,2816] = xg * WeguT_e^T (16x22/e)
//                    both store bf16.
// PHASE 1 (down):    job "shared": out += sgate-scaled h_sh * WsdT^T, split-K=4
//                    (atomic, 16x16x4 = 1024 blk)
//                    job "expert e": eo[slots,2048] = h_e * WedT_e^T (16x16/e, f32)
template <int PHASE>
__global__ __launch_bounds__(256)
void moe_gemm_kernel(const unsigned short* __restrict__ Ash,
                     const unsigned short* __restrict__ Bsh,
                     const unsigned short* __restrict__ Aex,
                     const unsigned short* __restrict__ Bex,
                     void* __restrict__ Csh, void* __restrict__ Cex,
                     const int* __restrict__ counts,
                     const int* __restrict__ offsets,
                     const float* __restrict__ rowscale) {
  // XCD-aware bijective block swizzle (gridDim.x % 8 == 0 by construction)
  int o = blockIdx.x;
  int b = (o & 7) * (gridDim.x >> 3) + (o >> 3);

  const unsigned short *A, *B;
  char* Cc;
  int N, Kld, nt, k0 = 0, row0, col0, rowbase = 0, cnt;
  bool expert;
  if constexpr (PHASE == 0) {
    if (b < 1408) {                       // 16 rowblk x 88 colblk
      expert = false; A = Ash; B = Bsh; Cc = (char*)Csh;
      N = 2 * ISH; Kld = H_DIM; nt = H_DIM / 32;
      row0 = (b & 15) * 128; col0 = (b >> 4) * 128; cnt = T_TOK;
    } else {                              // per expert: 16 rowblk x 22 colblk
      int b2 = b - 1408, e = b2 / 352, r2 = b2 % 352;
      cnt = counts[e]; row0 = (r2 & 15) * 128;
      if (row0 >= cnt) return;
      rowbase = offsets[e];
      expert = true; A = Aex; B = Bex + (long)e * 2 * IMOE * H_DIM; Cc = (char*)Cex;
      N = 2 * IMOE; Kld = H_DIM; nt = H_DIM / 32;
      col0 = (r2 >> 4) * 128;
    }
  } else {
    if (b < 1024) {                       // 16 x 16 x splitK4
      expert = false; A = Ash; B = Bsh; Cc = (char*)Csh;
      N = H_DIM; Kld = ISH; nt = (ISH / 4) / 32;
      row0 = (b & 15) * 128; col0 = ((b >> 4) & 15) * 128; k0 = (b >> 8) * (ISH / 4);
      cnt = T_TOK;
    } else {                              // per expert: 16 x 16
      int b2 = b - 1024, e = b2 >> 8, r2 = b2 & 255;
      cnt = counts[e]; row0 = (r2 & 15) * 128;
      if (row0 >= cnt) return;
      rowbase = offsets[e];
      expert = true; A = Aex; B = Bex + (long)e * H_DIM * IMOE; Cc = (char*)Cex;
      N = H_DIM; Kld = IMOE; nt = IMOE / 32;
      col0 = (r2 >> 4) * 128;
    }
  }

  __shared__ unsigned short As[128 * 32];
  __shared__ unsigned short Bs[128 * 32];

  int tid = threadIdx.x, wave = tid >> 6, lane = tid & 63;

  // staging: 16B chunk c -> LDS row c>>2, k-chunk c&3; global source k-chunk
  // pre-swizzled: (c&3) ^ ((row>>1)&3)  (rule 21: inverse swz on source)
  int c0 = wave * 64 + lane, c1 = c0 + 256;
  int ar0 = c0 >> 2, ar1 = c1 >> 2;
  int ak0 = (((c0 & 3) ^ ((ar0 >> 1) & 3)) * 8);
  int ak1 = (((c1 & 3) ^ ((ar1 >> 1) & 3)) * 8);

  const unsigned short* aS0 = A + (long)(rowbase + min(row0 + ar0, cnt - 1)) * Kld + k0 + ak0;
  const unsigned short* aS1 = A + (long)(rowbase + min(row0 + ar1, cnt - 1)) * Kld + k0 + ak1;
  const unsigned short* bS0 = B + (long)(col0 + ar0) * Kld + k0 + ak0;
  const unsigned short* bS1 = B + (long)(col0 + ar1) * Kld + k0 + ak1;

  unsigned short* lA0 = &As[wave * 512];
  unsigned short* lA1 = &As[(4 + wave) * 512];
  unsigned short* lB0 = &Bs[wave * 512];
  unsigned short* lB1 = &Bs[(4 + wave) * 512];

  int wr = (wave >> 1) * 64, wc = (wave & 1) * 64;
  int fr = lane & 15, fg = lane >> 4;
  int aAddr[4], bAddr[4];
#pragma unroll
  for (int m = 0; m < 4; m++) {
    int r = wr + m * 16 + fr;
    aAddr[m] = r * 32 + ((fg ^ ((r >> 1) & 3)) * 8);
    int r2 = wc + m * 16 + fr;
    bAddr[m] = r2 * 32 + ((fg ^ ((r2 >> 1) & 3)) * 8);
  }

  f32x4 acc[4][4] = {};

  for (int t = 0; t < nt; t++) {
    long kk = (long)t * 32;
    gload_lds16(aS0 + kk, lA0);
    gload_lds16(aS1 + kk, lA1);
    gload_lds16(bS0 + kk, lB0);
    gload_lds16(bS1 + kk, lB1);
    __syncthreads();
    short8 aF[4], bF[4];
#pragma unroll
    for (int m = 0; m < 4; m++) aF[m] = *(const short8*)&As[aAddr[m]];
#pragma unroll
    for (int n = 0; n < 4; n++) bF[n] = *(const short8*)&Bs[bAddr[n]];
#pragma unroll
    for (int m = 0; m < 4; m++)
#pragma unroll
      for (int n = 0; n < 4; n++)
        acc[m][n] = MFMA16(aF[m], bF[n], acc[m][n]);
    __syncthreads();
  }

  int rowguard = cnt - row0;
#pragma unroll
  for (int m = 0; m < 4; m++) {
    int rbase = wr + m * 16 + fg * 4;
#pragma unroll
    for (int n = 0; n < 4; n++) {
      int cg = col0 + wc + n * 16 + fr;
      f32x4 v = acc[m][n];
#pragma unroll
      for (int j = 0; j < 4; j++) {
        int rl = rbase + j;
        if (rl < rowguard) {
          long orow = (long)rowbase + row0 + rl;
          long ci = orow * (long)N + cg;
          if constexpr (PHASE == 0) {
            ((unsigned short*)Cc)[ci] = f2bf(v[j]);
          } else {
            if (!expert) unsafeAtomicAdd(&((float*)Cc)[ci], v[j] * rowscale[orow]);
            else         ((float*)Cc)[ci] = v[j];
          }
        }
      }
    }
  }
}

// ---------------- elementwise ----------------

// fused silu-mul over shared (2048 x 2*ISH -> h_sh) and expert (4096 x 2*IMOE -> h_e)
__global__ __launch_bounds__(256)
void silu2_kernel(const unsigned short* __restrict__ gu_sh, unsigned short* __restrict__ h_sh,
                  const unsigned short* __restrict__ gu_e, unsigned short* __restrict__ h_e) {
  int i = blockIdx.x * 256 + threadIdx.x;
  const int nsh = T_TOK * (ISH / 4);
  const unsigned short* g;
  unsigned short* h;
  int I, row, c4;
  if (i < nsh) {
    g = gu_sh; h = h_sh; I = ISH;
    row = i / (ISH / 4); c4 = i - row * (ISH / 4);
  } else {
    int j = i - nsh;
    g = gu_e; h = h_e; I = IMOE;
    row = j / (IMOE / 4); c4 = j - row * (IMOE / 4);
  }
  const unsigned short* gp = g + (long)row * 2 * I + c4 * 4;
  ushort4 gv = *(const ushort4*)gp;
  ushort4 uv = *(const ushort4*)(gp + I);
  ushort4 o;
  o.x = f2bf(silu_f(bf2f(gv.x)) * bf2f(uv.x));
  o.y = f2bf(silu_f(bf2f(gv.y)) * bf2f(uv.y));
  o.z = f2bf(silu_f(bf2f(gv.z)) * bf2f(uv.z));
  o.w = f2bf(silu_f(bf2f(gv.w)) * bf2f(uv.w));
  *(ushort4*)(h + (long)row * I + c4 * 4) = o;
}

// out += w0*eo[s0] + w1*eo[s1]   (out already holds gated shared-expert sum)
__global__ __launch_bounds__(256)
void combine_kernel(float* __restrict__ out, const float* __restrict__ eo,
                    const int* __restrict__ slot_of_tok, const float* __restrict__ rw) {
  int i = blockIdx.x * 256 + threadIdx.x;
  const int h4n = H_DIM / 4;
  if (i >= T_TOK * h4n) return;
  int t = i / h4n;
  int h4 = i - t * h4n;
  int s0 = slot_of_tok[t * 2], s1 = slot_of_tok[t * 2 + 1];
  float w0 = rw[t * 2], w1 = rw[t * 2 + 1];
  float4 o = ((float4*)out)[i];
  float4 a = ((const float4*)eo)[(long)s0 * h4n + h4];
  float4 b = ((const float4*)eo)[(long)s1 * h4n + h4];
  o.x += w0 * a.x + w1 * b.x;
  o.y += w0 * a.y + w1 * b.y;
  o.z += w0 * a.z + w1 * b.z;
  o.w += w0 * a.w + w1 * b.w;
  ((float4*)out)[i] = o;
}

// ---------------- host ----------------

extern "C" void kernel_launch(void* const* d_in, const int* in_sizes, int n_in,
                              void* d_out, int out_size, void* d_ws, size_t ws_size,
                              hipStream_t stream) {
  (void)in_sizes; (void)n_in; (void)out_size;
  const float* x    = (const float*)d_in[0];
  const float* Wr   = (const float*)d_in[1];
  const float* Wsg  = (const float*)d_in[2];
  const float* Wsgu = (const float*)d_in[3];
  const float* Wsd  = (const float*)d_in[4];
  const float* Wegu = (const float*)d_in[5];
  const float* Wed  = (const float*)d_in[6];
  float* out = (float*)d_out;

  char* ws = (char*)d_ws;
  size_t off = 0;
  auto alloc = [&](size_t b) { size_t o = off; off += (b + 255) & ~(size_t)255; return o; };

  size_t o_xbf   = alloc((size_t)T_TOK * H_DIM * 2);
  size_t o_WsguT = alloc((size_t)2 * ISH * H_DIM * 2);       // aliased as eo in phase 1
  size_t o_WsdT  = alloc((size_t)H_DIM * ISH * 2);
  size_t o_WeguT = alloc((size_t)NEXP * 2 * IMOE * H_DIM * 2);  // h_e aliases after phase 0
  size_t o_WedT  = alloc((size_t)NEXP * H_DIM * IMOE * 2);
  size_t o_gush  = alloc((size_t)T_TOK * 2 * ISH * 2);
  size_t o_hsh   = alloc((size_t)T_TOK * ISH * 2);
  size_t o_gue   = alloc((size_t)TK_TOT * 2 * IMOE * 2);
  size_t o_xg    = alloc((size_t)TK_TOT * H_DIM * 2);
  size_t o_ints  = alloc(256);
  size_t o_rw    = alloc((size_t)TK_TOT * 4);
  size_t o_sel   = alloc((size_t)TK_TOT * 4);
  size_t o_sg    = alloc((size_t)T_TOK * 4);
  size_t o_tok   = alloc((size_t)TK_TOT * 4);
  size_t o_s2t   = alloc((size_t)TK_TOT * 4);

  if (off > ws_size) {
    fprintf(stderr, "[moe kernel] workspace too small: need %zu have %zu\n", off, ws_size);
    return;
  }

  unsigned short* xbf   = (unsigned short*)(ws + o_xbf);
  unsigned short* WsguT = (unsigned short*)(ws + o_WsguT);
  unsigned short* WsdT  = (unsigned short*)(ws + o_WsdT);
  unsigned short* WeguT = (unsigned short*)(ws + o_WeguT);
  unsigned short* WedT  = (unsigned short*)(ws + o_WedT);
  unsigned short* gu_sh = (unsigned short*)(ws + o_gush);
  unsigned short* h_sh  = (unsigned short*)(ws + o_hsh);
  unsigned short* gu_e  = (unsigned short*)(ws + o_gue);
  unsigned short* xg    = (unsigned short*)(ws + o_xg);
  unsigned short* h_e   = (unsigned short*)(ws + o_WeguT);   // alias: WeguT dead after phase 0
  float* eo             = (float*)(ws + o_WsguT);            // alias: WsguT dead after phase 0

  int* counts  = (int*)(ws + o_ints);
  int* cursor  = counts + 8;
  int* offsets = counts + 16;
  float* rw    = (float*)(ws + o_rw);
  int* sel     = (int*)(ws + o_sel);
  float* sgate = (float*)(ws + o_sg);
  int* tok     = (int*)(ws + o_tok);
  int* s2t     = (int*)(ws + o_s2t);

  dim3 tb(32, 8, 1);

  hipMemsetAsync(counts, 0, 64, stream);
  hipMemsetAsync(out, 0, (size_t)T_TOK * H_DIM * 4, stream);

  transpose_cvt_kernel<<<dim3(2 * ISH / 32, H_DIM / 32, 1), tb, 0, stream>>>(
      Wsgu, WsguT, H_DIM, 2 * ISH, 0, 0);
  transpose_cvt_kernel<<<dim3(H_DIM / 32, ISH / 32, 1), tb, 0, stream>>>(
      Wsd, WsdT, ISH, H_DIM, 0, 0);
  transpose_cvt_kernel<<<dim3(2 * IMOE / 32, H_DIM / 32, NEXP), tb, 0, stream>>>(
      Wegu, WeguT, H_DIM, 2 * IMOE, (long)H_DIM * 2 * IMOE, (long)2 * IMOE * H_DIM);
  transpose_cvt_kernel<<<dim3(H_DIM / 32, IMOE / 32, NEXP), tb, 0, stream>>>(
      Wed, WedT, IMOE, H_DIM, (long)IMOE * H_DIM, (long)H_DIM * IMOE);

  cvt_x_kernel<<<(T_TOK * H_DIM / 4) / 256, 256, 0, stream>>>(x, xbf, T_TOK * H_DIM / 4);

  router_kernel<<<T_TOK, 256, 0, stream>>>(x, Wr, Wsg, rw, sel, sgate, counts);
  scan_kernel<<<1, 64, 0, stream>>>(counts, offsets);
  scatter_kernel<<<(T_TOK + 255) / 256, 256, 0, stream>>>(sel, offsets, cursor, tok, s2t);
  gather_kernel<<<TK_TOT, 256, 0, stream>>>(xbf, tok, xg);

  // fused gate-up: shared (1408 blocks) + experts (8 x 352) = 4224 blocks
  moe_gemm_kernel<0><<<4224, 256, 0, stream>>>(
      xbf, WsguT, xg, WeguT, gu_sh, gu_e, counts, offsets, nullptr);

  // fused silu over both tensors
  {
    int total = T_TOK * (ISH / 4) + TK_TOT * (IMOE / 4);
    silu2_kernel<<<total / 256, 256, 0, stream>>>(gu_sh, h_sh, gu_e, h_e);
  }

  // fused down: shared split-K=4 atomic (1024) + experts (8 x 256) = 3072 blocks
  moe_gemm_kernel<1><<<3072, 256, 0, stream>>>(
      h_sh, WsdT, h_e, WedT, out, eo, counts, offsets, sgate);

  combine_kernel<<<(T_TOK * H_DIM / 4) / 256, 256, 0, stream>>>(out, eo, s2t, rw);
}

// Round 4
// 856.708 us; speedup vs baseline: 1.1813x; 1.1813x over previous
//
#include <hip/hip_runtime.h>
#include <cstdio>

// Qwen2 MoE sparse block, MI355X gfx950.
// Round 4: faithful m201-style 256x256 8-phase GEMM (BK=64, 8 waves, 128KiB
// LDS 2dbuf x 2half, counted vmcnt(4) at phases 4/8 only, per-16B-granule
// XOR swizzle applied on global source + ds_read). Two fused GEMM dispatches
// (gate-up: shared+experts; down: shared+experts). No atomics.

#define H_DIM 2048
#define IMOE  1408
#define ISH   5632
#define NEXP  8
#define T_TOK 2048
#define TK_TOT (T_TOK * 2)

typedef __attribute__((ext_vector_type(8))) short short8;
typedef __attribute__((ext_vector_type(8))) __bf16 bf16x8;
typedef __attribute__((ext_vector_type(4))) float f32x4;

__device__ __forceinline__ float bf2f(unsigned short u) {
  union { unsigned int i; float f; } v; v.i = ((unsigned int)u) << 16; return v.f;
}
__device__ __forceinline__ unsigned short f2bf(float f) {
  union { float f; unsigned int i; } v; v.f = f;
  unsigned int x = v.i;
  return (unsigned short)((x + 0x7fffu + ((x >> 16) & 1u)) >> 16);
}

__device__ __forceinline__ f32x4 MFMA16(short8 a, short8 b, f32x4 c) {
  return __builtin_amdgcn_mfma_f32_16x16x32_bf16(
      __builtin_bit_cast(bf16x8, a), __builtin_bit_cast(bf16x8, b), c, 0, 0, 0);
}

__device__ __forceinline__ void gload_lds16(const unsigned short* g, unsigned short* l) {
  __builtin_amdgcn_global_load_lds(
      (const __attribute__((address_space(1))) unsigned int*)g,
      (__attribute__((address_space(3))) unsigned int*)l, 16, 0, 0);
}

__device__ __forceinline__ float silu_f(float x) { return x / (1.0f + __expf(-x)); }

#define SBAR()   asm volatile("s_barrier" ::: "memory")
#define VMCNT(n) asm volatile("s_waitcnt vmcnt(" #n ")" ::: "memory")
#define LGKM0()  asm volatile("s_waitcnt lgkmcnt(0)" ::: "memory")

// ---------------- conversion kernels ----------------

__global__ __launch_bounds__(256)
void transpose_cvt_kernel(const float* __restrict__ src, unsigned short* __restrict__ dst,
                          int R, int C, long sStride, long dStride) {
  src += (long)blockIdx.z * sStride;
  dst += (long)blockIdx.z * dStride;
  __shared__ float tile[32][33];
  int tx = threadIdx.x, ty = threadIdx.y;           // 32 x 8
  int x = blockIdx.x * 32 + tx;
  int yb = blockIdx.y * 32;
#pragma unroll
  for (int j = 0; j < 4; j++) {
    int y = yb + ty + j * 8;
    tile[ty + j * 8][tx] = src[(long)y * C + x];
  }
  __syncthreads();
  int c = blockIdx.x * 32 + ty;
  int r = yb + tx;
#pragma unroll
  for (int j = 0; j < 4; j++) {
    dst[(long)(c + j * 8) * R + r] = f2bf(tile[tx][ty + j * 8]);
  }
}

__global__ __launch_bounds__(256)
void cvt_x_kernel(const float* __restrict__ x, unsigned short* __restrict__ xb, int total4) {
  int i = blockIdx.x * 256 + threadIdx.x;
  if (i >= total4) return;
  float4 v = ((const float4*)x)[i];
  ushort4 o;
  o.x = f2bf(v.x); o.y = f2bf(v.y); o.z = f2bf(v.z); o.w = f2bf(v.w);
  ((ushort4*)xb)[i] = o;
}

// ---------------- routing ----------------

__global__ __launch_bounds__(256)
void router_kernel(const float* __restrict__ x, const float* __restrict__ Wr,
                   const float* __restrict__ Wsg, float* __restrict__ rw,
                   int* __restrict__ sel, float* __restrict__ sgate_sig,
                   int* __restrict__ counts) {
  int t = blockIdx.x;
  const float* xr = x + (long)t * H_DIM;
  float p[9];
#pragma unroll
  for (int e = 0; e < 9; e++) p[e] = 0.0f;
  for (int h = threadIdx.x; h < H_DIM; h += 256) {
    float xv = xr[h];
#pragma unroll
    for (int e = 0; e < 8; e++) p[e] += xv * Wr[e * H_DIM + h];
    p[8] += xv * Wsg[h];
  }
#pragma unroll
  for (int e = 0; e < 9; e++)
    for (int off = 32; off > 0; off >>= 1)
      p[e] += __shfl_down(p[e], off, 64);
  __shared__ float red[4][9];
  int wave = threadIdx.x >> 6, lane = threadIdx.x & 63;
  if (lane == 0) {
#pragma unroll
    for (int e = 0; e < 9; e++) red[wave][e] = p[e];
  }
  __syncthreads();
  if (threadIdx.x == 0) {
    float lg[9];
#pragma unroll
    for (int e = 0; e < 9; e++) lg[e] = red[0][e] + red[1][e] + red[2][e] + red[3][e];
    float m = lg[0];
#pragma unroll
    for (int e = 1; e < 8; e++) m = fmaxf(m, lg[e]);
    float pr[8], s = 0.0f;
#pragma unroll
    for (int e = 0; e < 8; e++) { pr[e] = expf(lg[e] - m); s += pr[e]; }
    float inv = 1.0f / s;
#pragma unroll
    for (int e = 0; e < 8; e++) pr[e] *= inv;
    int i0 = 0;
#pragma unroll
    for (int e = 1; e < 8; e++) if (pr[e] > pr[i0]) i0 = e;
    int i1 = (i0 == 0) ? 1 : 0;
#pragma unroll
    for (int e = 0; e < 8; e++) if (e != i0 && pr[e] > pr[i1]) i1 = e;
    rw[t * 2] = pr[i0]; rw[t * 2 + 1] = pr[i1];
    sel[t * 2] = i0;    sel[t * 2 + 1] = i1;
    sgate_sig[t] = 1.0f / (1.0f + expf(-lg[8]));
    atomicAdd(&counts[i0], 1);
    atomicAdd(&counts[i1], 1);
  }
}

__global__ void scan_kernel(const int* __restrict__ counts, int* __restrict__ offsets) {
  if (threadIdx.x == 0 && blockIdx.x == 0) {
    int s = 0;
    for (int e = 0; e < NEXP; e++) { offsets[e] = s; s += counts[e]; }
    offsets[NEXP] = s;
  }
}

__global__ __launch_bounds__(256)
void scatter_kernel(const int* __restrict__ sel, const int* __restrict__ offsets,
                    int* __restrict__ cursor, int* __restrict__ tok_of_slot,
                    int* __restrict__ slot_of_tok) {
  int t = blockIdx.x * 256 + threadIdx.x;
  if (t >= T_TOK) return;
#pragma unroll
  for (int k = 0; k < 2; k++) {
    int e = sel[t * 2 + k];
    int pos = atomicAdd(&cursor[e], 1);
    int slot = offsets[e] + pos;
    tok_of_slot[slot] = t;
    slot_of_tok[t * 2 + k] = slot;
  }
}

__global__ __launch_bounds__(256)
void gather_kernel(const unsigned short* __restrict__ xbf, const int* __restrict__ tok,
                   unsigned short* __restrict__ xg) {
  int i = blockIdx.x * 256 + threadIdx.x;   // slot*256 + col16B
  int slot = i >> 8, c8 = i & 255;
  long src = (long)tok[slot] * H_DIM + c8 * 8;
  ulonglong2 v = *(const ulonglong2*)(xbf + src);
  ((ulonglong2*)xg)[i] = v;
}

// ---------------- 256x256 8-phase GEMM (m201 template) ----------------
// C[M,N] = A[M,K](bf16) * BT[N,K]^T(bf16).  512 thr = 8 waves (2M x 4N),
// wave tile 128x64. BK=64, LDS: A[2dbuf][2half][128][64] + B same = 128 KiB.
// Swizzle: 16B granule g at row r lives at LDS granule g ^ (r&7); inverse
// applied on the per-lane global source (rule 21), forward on ds_read.
// Iteration i computes K-tiles t0=2i (dbuf0, phases 0-3) and t0+1 (dbuf1,
// phases 4-7); each phase stages one half-tile:
//   ph0:A(1,0)<-t0+1  ph1:A(1,1)<-t0+1  ph2:B(0,0)<-t0+2  ph3:B(0,1)<-t0+2
//   ph4:A(0,0)<-t0+2  ph5:A(0,1)<-t0+2  ph6:B(1,0)<-t0+3  ph7:B(1,1)<-t0+3
// vmcnt(4) before the trailing barrier of ph3 and ph7 (2 ops/stage, keep 2
// newest stages in flight). WAR: every region staged >=1 phase after its
// last read. EPI: 0 = bf16 store, 1 = f32 * rowscale[row], 2 = f32 store.
template <int PHASE>
__global__ __launch_bounds__(512, 2)
void moe_gemm8_kernel(const unsigned short* __restrict__ Ash,
                      const unsigned short* __restrict__ Bsh,
                      const unsigned short* __restrict__ Aex,
                      const unsigned short* __restrict__ Bex,
                      void* __restrict__ Csh, void* __restrict__ Cex,
                      const int* __restrict__ counts,
                      const int* __restrict__ offsets,
                      const float* __restrict__ rowscale) {
  // XCD-aware bijective swizzle (grid % 8 == 0)
  int o = blockIdx.x;
  int b = (o & 7) * (gridDim.x >> 3) + (o >> 3);

  const unsigned short *A, *B;
  char* Cc;
  int N, Kld, NT, row0, col0, rowbase = 0, cnt;
  int epi;   // 0 bf16, 1 f32*rowscale, 2 f32
  if constexpr (PHASE == 0) {
    if (b < 352) {                       // shared gate-up: 8 x 44
      A = Ash; B = Bsh; Cc = (char*)Csh; epi = 0;
      N = 2 * ISH; Kld = H_DIM; NT = H_DIM / 64;
      row0 = (b & 7) * 256; col0 = (b >> 3) * 256; cnt = T_TOK;
    } else {                             // expert gate-up: 8 x 11 per expert
      int b2 = b - 352, e = b2 / 88, r2 = b2 % 88;
      cnt = counts[e]; row0 = (r2 & 7) * 256;
      if (row0 >= cnt) return;
      rowbase = offsets[e];
      A = Aex; B = Bex + (long)e * 2 * IMOE * H_DIM; Cc = (char*)Cex; epi = 0;
      N = 2 * IMOE; Kld = H_DIM; NT = H_DIM / 64;
      col0 = (r2 >> 3) * 256;
    }
  } else {
    if (b < 64) {                        // shared down: 8 x 8
      A = Ash; B = Bsh; Cc = (char*)Csh; epi = 1;
      N = H_DIM; Kld = ISH; NT = ISH / 64;
      row0 = (b & 7) * 256; col0 = (b >> 3) * 256; cnt = T_TOK;
    } else {                             // expert down: 8 x 8 per expert
      int b2 = b - 64, e = b2 >> 6, r2 = b2 & 63;
      cnt = counts[e]; row0 = (r2 & 7) * 256;
      if (row0 >= cnt) return;
      rowbase = offsets[e];
      A = Aex; B = Bex + (long)e * H_DIM * IMOE; Cc = (char*)Cex; epi = 2;
      N = H_DIM; Kld = IMOE; NT = IMOE / 64;
      col0 = (r2 >> 3) * 256;
    }
  }

  __shared__ unsigned short lds8[65536];   // 128 KiB (shorts)

  int tid = threadIdx.x, wave = tid >> 6, lane = tid & 63;
  int wr = wave >> 2, wc = wave & 3;
  int fr = lane & 15, fg = lane >> 4;

  // ds_read constant offsets (shorts): frag (m|n, k) at base + idx*1024 + cK[k]
  int cK[2];
  cK[0] = fr * 64 + ((fg ^ (fr & 7)) * 8);
  cK[1] = fr * 64 + (((4 + fg) ^ (fr & 7)) * 8);
  int aBase = wr * 8192;                                   // + d*16384
  int bBase = 32768 + (wc >> 1) * 8192 + (wc & 1) * 4096;  // + d*16384

  // staging source pointers [half][site], inverse-swizzled granule
  const unsigned short *pA[2][2], *pB[2][2];
#pragma unroll
  for (int h = 0; h < 2; h++)
#pragma unroll
    for (int s = 0; s < 2; s++) {
      int hr = s * 64 + wave * 8 + (lane >> 3);
      int g = (lane & 7) ^ (hr & 7);
      long ra = row0 + h * 128 + hr;
      if (ra > cnt - 1) ra = cnt - 1;           // clamp (expert tails)
      ra += rowbase;
      pA[h][s] = A + ra * (long)Kld + g * 8;
      pB[h][s] = B + (long)(col0 + h * 128 + hr) * Kld + g * 8;
    }

#define STG_A(d, h, tile) do { long ko = (long)(tile) * 64; \
    gload_lds16(pA[h][0] + ko, &lds8[(d)*16384 + (h)*8192 + wave*512]); \
    gload_lds16(pA[h][1] + ko, &lds8[(d)*16384 + (h)*8192 + 4096 + wave*512]); } while (0)
#define STG_B(d, h, tile) do { long ko = (long)(tile) * 64; \
    gload_lds16(pB[h][0] + ko, &lds8[32768 + (d)*16384 + (h)*8192 + wave*512]); \
    gload_lds16(pB[h][1] + ko, &lds8[32768 + (d)*16384 + (h)*8192 + 4096 + wave*512]); } while (0)

  short8 aReg[4][2], bReg[4][2];
  f32x4 acc[8][4] = {};

#define LDA(mh, d) do { _Pragma("unroll") for (int mi = 0; mi < 4; mi++) \
    _Pragma("unroll") for (int k = 0; k < 2; k++) \
      aReg[mi][k] = *(const short8*)&lds8[(d)*16384 + aBase + ((mh)*4 + mi)*1024 + cK[k]]; } while (0)
#define LDB(nh, d) do { _Pragma("unroll") for (int ni = 0; ni < 2; ni++) \
    _Pragma("unroll") for (int k = 0; k < 2; k++) \
      bReg[(nh)*2 + ni][k] = *(const short8*)&lds8[(d)*16384 + bBase + ((nh)*2 + ni)*1024 + cK[k]]; } while (0)
#define MM(mh, nh) do { _Pragma("unroll") for (int mi = 0; mi < 4; mi++) \
    _Pragma("unroll") for (int ni = 0; ni < 2; ni++) \
    _Pragma("unroll") for (int k = 0; k < 2; k++) \
      acc[(mh)*4 + mi][(nh)*2 + ni] = \
          MFMA16(aReg[mi][k], bReg[(nh)*2 + ni][k], acc[(mh)*4 + mi][(nh)*2 + ni]); } while (0)
#define PH_MID() do { SBAR(); LGKM0(); __builtin_amdgcn_s_setprio(1); } while (0)
#define PH_END() do { __builtin_amdgcn_s_setprio(0); SBAR(); } while (0)

  // prologue = virtual iter -1, phases 2..7
  STG_B(0, 0, 0); STG_B(0, 1, 0);
  STG_A(0, 0, 0); STG_A(0, 1, 0);
  STG_B(1, 0, 1); STG_B(1, 1, 1);
  VMCNT(4);
  SBAR();

  int NI = NT >> 1;
  for (int i = 0; i < NI; i++) {
    int t1 = 2 * i + 1;
    int t2 = 2 * i + 2; if (t2 > NT - 1) t2 = NT - 1;
    int t3 = 2 * i + 3; if (t3 > NT - 1) t3 = NT - 1;
    // ph0
    LDA(0, 0); LDB(0, 0); STG_A(1, 0, t1);
    PH_MID(); MM(0, 0); PH_END();
    // ph1
    LDB(1, 0); STG_A(1, 1, t1);
    PH_MID(); MM(0, 1); PH_END();
    // ph2
    LDA(1, 0); STG_B(0, 0, t2);
    PH_MID(); MM(1, 0); PH_END();
    // ph3
    STG_B(0, 1, t2);
    PH_MID(); MM(1, 1);
    __builtin_amdgcn_s_setprio(0); VMCNT(4); SBAR();
    // ph4
    LDA(0, 1); LDB(0, 1); STG_A(0, 0, t2);
    PH_MID(); MM(0, 0); PH_END();
    // ph5
    LDB(1, 1); STG_A(0, 1, t2);
    PH_MID(); MM(0, 1); PH_END();
    // ph6
    LDA(1, 1); STG_B(1, 0, t3);
    PH_MID(); MM(1, 0); PH_END();
    // ph7
    STG_B(1, 1, t3);
    PH_MID(); MM(1, 1);
    __builtin_amdgcn_s_setprio(0); VMCNT(4); SBAR();
  }
  VMCNT(0);

  // ---- epilogue ----
  int rowguard = cnt - row0;
#pragma unroll
  for (int m = 0; m < 8; m++) {
    int rl = wr * 128 + m * 16 + fg * 4;
#pragma unroll
    for (int n = 0; n < 4; n++) {
      int cg = col0 + wc * 64 + n * 16 + fr;
      f32x4 v = acc[m][n];
#pragma unroll
      for (int j = 0; j < 4; j++) {
        int r = rl + j;
        if (r < rowguard) {
          long orow = (long)rowbase + row0 + r;
          long ci = orow * (long)N + cg;
          if (epi == 0)      ((unsigned short*)Cc)[ci] = f2bf(v[j]);
          else if (epi == 1) ((float*)Cc)[ci] = v[j] * rowscale[orow];
          else               ((float*)Cc)[ci] = v[j];
        }
      }
    }
  }
#undef STG_A
#undef STG_B
#undef LDA
#undef LDB
#undef MM
#undef PH_MID
#undef PH_END
}

// ---------------- elementwise ----------------

__global__ __launch_bounds__(256)
void silu2_kernel(const unsigned short* __restrict__ gu_sh, unsigned short* __restrict__ h_sh,
                  const unsigned short* __restrict__ gu_e, unsigned short* __restrict__ h_e) {
  int i = blockIdx.x * 256 + threadIdx.x;
  const int nsh = T_TOK * (ISH / 4);
  const unsigned short* g;
  unsigned short* h;
  int I, row, c4;
  if (i < nsh) {
    g = gu_sh; h = h_sh; I = ISH;
    row = i / (ISH / 4); c4 = i - row * (ISH / 4);
  } else {
    int j = i - nsh;
    g = gu_e; h = h_e; I = IMOE;
    row = j / (IMOE / 4); c4 = j - row * (IMOE / 4);
  }
  const unsigned short* gp = g + (long)row * 2 * I + c4 * 4;
  ushort4 gv = *(const ushort4*)gp;
  ushort4 uv = *(const ushort4*)(gp + I);
  ushort4 o2;
  o2.x = f2bf(silu_f(bf2f(gv.x)) * bf2f(uv.x));
  o2.y = f2bf(silu_f(bf2f(gv.y)) * bf2f(uv.y));
  o2.z = f2bf(silu_f(bf2f(gv.z)) * bf2f(uv.z));
  o2.w = f2bf(silu_f(bf2f(gv.w)) * bf2f(uv.w));
  *(ushort4*)(h + (long)row * I + c4 * 4) = o2;
}

// out = out(shared, gated) + w0*eo[s0] + w1*eo[s1]
__global__ __launch_bounds__(256)
void combine_kernel(float* __restrict__ out, const float* __restrict__ eo,
                    const int* __restrict__ slot_of_tok, const float* __restrict__ rw) {
  int i = blockIdx.x * 256 + threadIdx.x;
  const int h4n = H_DIM / 4;
  if (i >= T_TOK * h4n) return;
  int t = i / h4n;
  int h4 = i - t * h4n;
  int s0 = slot_of_tok[t * 2], s1 = slot_of_tok[t * 2 + 1];
  float w0 = rw[t * 2], w1 = rw[t * 2 + 1];
  float4 o = ((float4*)out)[i];
  float4 a = ((const float4*)eo)[(long)s0 * h4n + h4];
  float4 b = ((const float4*)eo)[(long)s1 * h4n + h4];
  o.x += w0 * a.x + w1 * b.x;
  o.y += w0 * a.y + w1 * b.y;
  o.z += w0 * a.z + w1 * b.z;
  o.w += w0 * a.w + w1 * b.w;
  ((float4*)out)[i] = o;
}

// ---------------- host ----------------

extern "C" void kernel_launch(void* const* d_in, const int* in_sizes, int n_in,
                              void* d_out, int out_size, void* d_ws, size_t ws_size,
                              hipStream_t stream) {
  (void)in_sizes; (void)n_in; (void)out_size;
  const float* x    = (const float*)d_in[0];
  const float* Wr   = (const float*)d_in[1];
  const float* Wsg  = (const float*)d_in[2];
  const float* Wsgu = (const float*)d_in[3];
  const float* Wsd  = (const float*)d_in[4];
  const float* Wegu = (const float*)d_in[5];
  const float* Wed  = (const float*)d_in[6];
  float* out = (float*)d_out;

  char* ws = (char*)d_ws;
  size_t off = 0;
  auto alloc = [&](size_t b) { size_t o = off; off += (b + 255) & ~(size_t)255; return o; };

  size_t o_xbf   = alloc((size_t)T_TOK * H_DIM * 2);
  size_t o_WsguT = alloc((size_t)2 * ISH * H_DIM * 2);          // aliased as eo in phase 1
  size_t o_WsdT  = alloc((size_t)H_DIM * ISH * 2);
  size_t o_WeguT = alloc((size_t)NEXP * 2 * IMOE * H_DIM * 2);  // h_e aliases after phase 0
  size_t o_WedT  = alloc((size_t)NEXP * H_DIM * IMOE * 2);
  size_t o_gush  = alloc((size_t)T_TOK * 2 * ISH * 2);
  size_t o_hsh   = alloc((size_t)T_TOK * ISH * 2);
  size_t o_gue   = alloc((size_t)TK_TOT * 2 * IMOE * 2);
  size_t o_xg    = alloc((size_t)TK_TOT * H_DIM * 2);
  size_t o_ints  = alloc(256);
  size_t o_rw    = alloc((size_t)TK_TOT * 4);
  size_t o_sel   = alloc((size_t)TK_TOT * 4);
  size_t o_sg    = alloc((size_t)T_TOK * 4);
  size_t o_tok   = alloc((size_t)TK_TOT * 4);
  size_t o_s2t   = alloc((size_t)TK_TOT * 4);

  if (off > ws_size) {
    fprintf(stderr, "[moe kernel] workspace too small: need %zu have %zu\n", off, ws_size);
    return;
  }

  unsigned short* xbf   = (unsigned short*)(ws + o_xbf);
  unsigned short* WsguT = (unsigned short*)(ws + o_WsguT);
  unsigned short* WsdT  = (unsigned short*)(ws + o_WsdT);
  unsigned short* WeguT = (unsigned short*)(ws + o_WeguT);
  unsigned short* WedT  = (unsigned short*)(ws + o_WedT);
  unsigned short* gu_sh = (unsigned short*)(ws + o_gush);
  unsigned short* h_sh  = (unsigned short*)(ws + o_hsh);
  unsigned short* gu_e  = (unsigned short*)(ws + o_gue);
  unsigned short* xg    = (unsigned short*)(ws + o_xg);
  unsigned short* h_e   = (unsigned short*)(ws + o_WeguT);   // alias: dead after phase 0
  float* eo             = (float*)(ws + o_WsguT);            // alias: dead after phase 0

  int* counts  = (int*)(ws + o_ints);
  int* cursor  = counts + 8;
  int* offsets = counts + 16;
  float* rw    = (float*)(ws + o_rw);
  int* sel     = (int*)(ws + o_sel);
  float* sgate = (float*)(ws + o_sg);
  int* tok     = (int*)(ws + o_tok);
  int* s2t     = (int*)(ws + o_s2t);

  dim3 tb(32, 8, 1);

  hipMemsetAsync(counts, 0, 64, stream);

  transpose_cvt_kernel<<<dim3(2 * ISH / 32, H_DIM / 32, 1), tb, 0, stream>>>(
      Wsgu, WsguT, H_DIM, 2 * ISH, 0, 0);
  transpose_cvt_kernel<<<dim3(H_DIM / 32, ISH / 32, 1), tb, 0, stream>>>(
      Wsd, WsdT, ISH, H_DIM, 0, 0);
  transpose_cvt_kernel<<<dim3(2 * IMOE / 32, H_DIM / 32, NEXP), tb, 0, stream>>>(
      Wegu, WeguT, H_DIM, 2 * IMOE, (long)H_DIM * 2 * IMOE, (long)2 * IMOE * H_DIM);
  transpose_cvt_kernel<<<dim3(H_DIM / 32, IMOE / 32, NEXP), tb, 0, stream>>>(
      Wed, WedT, IMOE, H_DIM, (long)IMOE * H_DIM, (long)H_DIM * IMOE);

  cvt_x_kernel<<<(T_TOK * H_DIM / 4) / 256, 256, 0, stream>>>(x, xbf, T_TOK * H_DIM / 4);

  router_kernel<<<T_TOK, 256, 0, stream>>>(x, Wr, Wsg, rw, sel, sgate, counts);
  scan_kernel<<<1, 64, 0, stream>>>(counts, offsets);
  scatter_kernel<<<(T_TOK + 255) / 256, 256, 0, stream>>>(sel, offsets, cursor, tok, s2t);
  gather_kernel<<<TK_TOT, 256, 0, stream>>>(xbf, tok, xg);

  // fused gate-up: shared (352) + experts (8 x 88) = 1056 blocks
  moe_gemm8_kernel<0><<<1056, 512, 0, stream>>>(
      xbf, WsguT, xg, WeguT, gu_sh, gu_e, counts, offsets, nullptr);

  {
    int total = T_TOK * (ISH / 4) + TK_TOT * (IMOE / 4);
    silu2_kernel<<<total / 256, 256, 0, stream>>>(gu_sh, h_sh, gu_e, h_e);
  }

  // fused down: shared (64, gated store) + experts (8 x 64) = 576 blocks
  moe_gemm8_kernel<1><<<576, 512, 0, stream>>>(
      h_sh, WsdT, h_e, WedT, out, eo, counts, offsets, sgate);

  combine_kernel<<<(T_TOK * H_DIM / 4) / 256, 256, 0, stream>>>(out, eo, s2t, rw);
}